// Round 5
// baseline (176.551 us; speedup 1.0000x reference)
//
#include <hip/hip_runtime.h>
#include <hip/hip_cooperative_groups.h>
#include <math.h>

namespace cg = cooperative_groups;

// Problem constants (fixed by setup_inputs)
constexpr int B       = 2;
constexpr int N       = 32768;
constexpr int D       = 3;
constexpr int M_FULL  = 8192;
constexpr int SUBDIV  = 8;
constexpr int M       = M_FULL / SUBDIV;   // 1024 subsampled verts per (b,d)
constexpr int K       = 512;               // value buckets over [-4,4]
constexpr float LO    = -4.0f;
constexpr float INV_W = 64.0f;             // 1 / (8/512)
constexpr int BLOCK   = 256;
constexpr int CHUNKS  = N / BLOCK;         // 128 blocks per (b,d) pair
constexpr int GRID    = B * D * CHUNKS;    // 768
constexpr float K4    = 5.770780163555852f; // 4*log2(e): e^{4t} = 2^{K4*t}

// Table layout per pair (8192 floats = 32 KB in d_ws, mirrored 1:1 in LDS):
//   [0]    sV    [1024] sAp   [2048] sSp   [3072] sAm   [4096] sSm
//   [5120] gAp(excl-pre) [5632] gSp(excl-pre) [6144] gAm(incl-suf) [6656] gSm(incl-suf)
//   [7168] beg(int) [7680] cnt(int)       -> 8192 floats. (+512 LDS-only: cur)
constexpr int TSTRIDE = 8192;

// ---- 512-element wave-parallel scans (one wave, lane owns 8 slots) ----
__device__ inline void scan512_pre(float* a) {   // exclusive prefix, small-first
    const int lane = threadIdx.x & 63;
    const int base = lane * 8;
    float xv[8], e[8]; float ls = 0.f;
    #pragma unroll
    for (int t = 0; t < 8; ++t) xv[t] = a[base + t];
    #pragma unroll
    for (int t = 0; t < 8; ++t) { e[t] = ls; ls += xv[t]; }
    float inc = ls;
    #pragma unroll
    for (int off = 1; off < 64; off <<= 1) {
        const float tmp = __shfl_up(inc, off, 64);
        if (lane >= off) inc += tmp;
    }
    const float exoff = inc - ls;
    #pragma unroll
    for (int t = 0; t < 8; ++t) a[base + t] = exoff + e[t];
}

__device__ inline void scan512_suf(float* a) {   // inclusive suffix, small-first
    const int lane = threadIdx.x & 63;
    const int base = lane * 8;
    float xv[8], e[8]; float ls = 0.f;
    #pragma unroll
    for (int t = 0; t < 8; ++t) xv[t] = a[base + t];
    #pragma unroll
    for (int t = 7; t >= 0; --t) { e[t] = ls; ls += xv[t]; }
    float inc = ls;
    #pragma unroll
    for (int off = 1; off < 64; off <<= 1) {
        const float tmp = __shfl_down(inc, off, 64);
        if (lane + off < 64) inc += tmp;
    }
    const float exoff = inc - ls;
    #pragma unroll
    for (int t = 0; t < 8; ++t) a[base + t] = exoff + e[t] + xv[t];
}

__device__ inline void scan512_i(const int* cntA, int* begA, int* curA) {
    const int lane = threadIdx.x & 63;
    const int base = lane * 8;
    int xv[8], e[8]; int ls = 0;
    #pragma unroll
    for (int t = 0; t < 8; ++t) xv[t] = cntA[base + t];
    #pragma unroll
    for (int t = 0; t < 8; ++t) { e[t] = ls; ls += xv[t]; }
    int inc = ls;
    #pragma unroll
    for (int off = 1; off < 64; off <<= 1) {
        const int tmp = __shfl_up(inc, off, 64);
        if (lane >= off) inc += tmp;
    }
    const int exoff = inc - ls;
    #pragma unroll
    for (int t = 0; t < 8; ++t) {
        begA[base + t] = exoff + e[t];
        curA[base + t] = exoff + e[t];
    }
}

// ---- shared device code: build tables into LDS (one block, one pair) ----
__device__ inline void build_tables(const float* __restrict__ dverts,
                                    const float* __restrict__ mverts,
                                    int b, int d,
                                    float* sV, float* sAp, float* sSp,
                                    float* sAm, float* sSm,
                                    float* gAp, float* gSp, float* gAm, float* gSm,
                                    int* cnt, int* beg, int* cur)
{
    const int tid = threadIdx.x;
    for (int i = tid; i < K; i += BLOCK) {
        cnt[i] = 0; gAp[i] = 0.f; gSp[i] = 0.f; gAm[i] = 0.f; gSm[i] = 0.f;
    }
    __syncthreads();

    float vv[4], ap[4], sp[4], am[4], sm[4]; int bj[4];
    #pragma unroll
    for (int u = 0; u < 4; ++u) {
        const int i = tid + u * BLOCK;
        const int g = (b * M_FULL + i * SUBDIV) * D + d;
        const float v = dverts[g];
        const float w = mverts[g];
        const float epv = __builtin_amdgcn_exp2f( K4 * v);   // e^{4v}
        const float emv = __builtin_amdgcn_exp2f(-K4 * v);   // e^{-4v}
        vv[u] = v;
        ap[u] = w * epv; sp[u] = epv;
        am[u] = w * emv; sm[u] = emv;
        int j = (int)floorf((v - LO) * INV_W);
        j = j < 0 ? 0 : (j > K - 1 ? K - 1 : j);
        bj[u] = j;
        atomicAdd(&cnt[j], 1);
        atomicAdd(&gAp[j], ap[u]);
        atomicAdd(&gSp[j], sp[u]);
        atomicAdd(&gAm[j], am[u]);
        atomicAdd(&gSm[j], sm[u]);
    }
    __syncthreads();

    const int wid = tid >> 6;
    if (wid == 0)      { scan512_i(cnt, beg, cur); scan512_suf(gSm); }
    else if (wid == 1) scan512_pre(gAp);
    else if (wid == 2) scan512_pre(gSp);
    else               scan512_suf(gAm);
    __syncthreads();

    #pragma unroll
    for (int u = 0; u < 4; ++u) {
        const int pos = atomicAdd(&cur[bj[u]], 1);
        sV[pos] = vv[u]; sAp[pos] = ap[u]; sSp[pos] = sp[u];
        sAm[pos] = am[u]; sSm[pos] = sm[u];
    }
    __syncthreads();
}

// ---- shared device code: one query per thread from LDS tables ----
__device__ inline void run_query(const float* __restrict__ x,
                                 float* __restrict__ out,
                                 int b, int d, int c,
                                 const float* sV, const float* sAp, const float* sSp,
                                 const float* sAm, const float* sSm,
                                 const float* gAp, const float* gSp,
                                 const float* gAm, const float* gSm,
                                 const int* cnt, const int* beg)
{
    const int tid = threadIdx.x;
    const int n = c * BLOCK + tid;
    const int o = (b * N + n) * D + d;
    const float xq = x[o];

    int j = (int)floorf((xq - LO) * INV_W);
    j = j < 0 ? 0 : (j > K - 1 ? K - 1 : j);

    const float en  = __builtin_amdgcn_exp2f(-K4 * xq);  // e^{-4x}
    const float epx = __builtin_amdgcn_exp2f( K4 * xq);  // e^{+4x}

    const float Ap = gAp[j];
    const float Sp = gSp[j];
    const float Am = (j < K - 1) ? gAm[j + 1] : 0.f;
    const float Sm = (j < K - 1) ? gSm[j + 1] : 0.f;

    const int s0 = beg[j], s1 = s0 + cnt[j];
    float rAp = 0.f, rSp = 0.f, rAm = 0.f, rSm = 0.f;
    for (int i = s0; i < s1; ++i) {
        const bool le = (sV[i] <= xq);
        rAp += le ? sAp[i] : 0.f;
        rSp += le ? sSp[i] : 0.f;
        rAm += le ? 0.f : sAm[i];
        rSm += le ? 0.f : sSm[i];
    }
    out[o] = (en * (Ap + rAp) + epx * (Am + rAm)) /
             (en * (Sp + rSp) + epx * (Sm + rSm));
}

// ================= cooperative single-launch version =================
__global__ __launch_bounds__(BLOCK) void deformer_coop(
    const float* __restrict__ x,
    const float* __restrict__ dverts,
    const float* __restrict__ mverts,
    float* __restrict__ out,
    float* __restrict__ tab)
{
    __shared__ __align__(16) float lds[TSTRIDE + K];   // 34 KB, mirrors ws layout
    float* sV  = lds;          float* sAp = lds + 1024;
    float* sSp = lds + 2048;   float* sAm = lds + 3072;
    float* sSm = lds + 4096;
    float* gAp = lds + 5120;   float* gSp = lds + 5632;
    float* gAm = lds + 6144;   float* gSm = lds + 6656;
    int*   beg = (int*)(lds + 7168);
    int*   cnt = (int*)(lds + 7680);
    int*   cur = (int*)(lds + TSTRIDE);   // LDS-only scratch

    const int tid = threadIdx.x;
    const int p = blockIdx.x >> 7;    // pair 0..5
    const int c = blockIdx.x & 127;   // chunk within pair
    const int b = p / 3, d = p % 3;
    float* tp = tab + p * TSTRIDE;

    if (c == 0) {
        build_tables(dverts, mverts, b, d, sV, sAp, sSp, sAm, sSm,
                     gAp, gSp, gAm, gSm, cnt, beg, cur);
        // publish: 8192 floats, coalesced
        for (int i = tid; i < 2048; i += BLOCK)
            reinterpret_cast<float4*>(tp)[i] =
                reinterpret_cast<const float4*>(lds)[i];
    }

    cg::this_grid().sync();   // device-scope fence + grid barrier

    if (c != 0) {
        for (int i = tid; i < 2048; i += BLOCK)
            reinterpret_cast<float4*>(lds)[i] =
                reinterpret_cast<const float4*>(tp)[i];
        __syncthreads();
    }

    run_query(x, out, b, d, c, sV, sAp, sSp, sAm, sSm,
              gAp, gSp, gAm, gSm, cnt, beg);
}

// ================= fallback: proven R4 single-block-build version =================
__global__ __launch_bounds__(BLOCK) void deformer_one(
    const float* __restrict__ x,
    const float* __restrict__ dverts,
    const float* __restrict__ mverts,
    float* __restrict__ out)
{
    __shared__ __align__(16) float lds[TSTRIDE + K];
    float* sV  = lds;          float* sAp = lds + 1024;
    float* sSp = lds + 2048;   float* sAm = lds + 3072;
    float* sSm = lds + 4096;
    float* gAp = lds + 5120;   float* gSp = lds + 5632;
    float* gAm = lds + 6144;   float* gSm = lds + 6656;
    int*   beg = (int*)(lds + 7168);
    int*   cnt = (int*)(lds + 7680);
    int*   cur = (int*)(lds + TSTRIDE);

    const int p = blockIdx.x >> 7;
    const int c = blockIdx.x & 127;
    const int b = p / 3, d = p % 3;

    build_tables(dverts, mverts, b, d, sV, sAp, sSp, sAm, sSm,
                 gAp, gSp, gAm, gSm, cnt, beg, cur);
    run_query(x, out, b, d, c, sV, sAp, sSp, sAm, sSm,
              gAp, gSp, gAm, gSm, cnt, beg);
}

extern "C" void kernel_launch(void* const* d_in, const int* in_sizes, int n_in,
                              void* d_out, int out_size, void* d_ws, size_t ws_size,
                              hipStream_t stream) {
    const float* x  = (const float*)d_in[0];
    const float* dv = (const float*)d_in[1];
    const float* mv = (const float*)d_in[2];
    float* out = (float*)d_out;
    float* tab = (float*)d_ws;    // 192 KB used

    void* args[] = { (void*)&x, (void*)&dv, (void*)&mv, (void*)&out, (void*)&tab };
    hipError_t e = hipLaunchCooperativeKernel(
        reinterpret_cast<void*>(deformer_coop),
        dim3(GRID), dim3(BLOCK), args, 0, stream);
    if (e != hipSuccess) {
        // cooperative launch unavailable (e.g. under capture) -> proven path
        deformer_one<<<GRID, BLOCK, 0, stream>>>(x, dv, mv, out);
    }
}

// Round 6
// 73.418 us; speedup vs baseline: 2.4047x; 2.4047x over previous
//
#include <hip/hip_runtime.h>
#include <math.h>

// Problem constants (fixed by setup_inputs)
constexpr int B       = 2;
constexpr int N       = 32768;
constexpr int D       = 3;
constexpr int M_FULL  = 8192;
constexpr int SUBDIV  = 8;
constexpr int M       = M_FULL / SUBDIV;   // 1024 subsampled verts per (b,d)
constexpr int K       = 512;               // value buckets over [-4,4]
constexpr float LO    = -4.0f;
constexpr float INV_W = 64.0f;             // 1 / (8/512)
constexpr int BLOCK   = 256;
constexpr int QPT     = 4;                 // queries per thread
constexpr int CHUNKS  = N / (BLOCK * QPT); // 32 blocks per (b,d) pair
constexpr int GRID    = B * D * CHUNKS;    // 192 blocks -> <=1 per CU, no build contention
constexpr float K4    = 5.770780163555852f; // 4*log2(e): e^{4t} = 2^{K4*t}

// ---- 512-element wave-parallel scans (one wave, lane owns 8 slots) ----
__device__ inline void scan512_pre(float* a) {   // exclusive prefix, small-first
    const int lane = threadIdx.x & 63;
    const int base = lane * 8;
    float xv[8], e[8]; float ls = 0.f;
    #pragma unroll
    for (int t = 0; t < 8; ++t) xv[t] = a[base + t];
    #pragma unroll
    for (int t = 0; t < 8; ++t) { e[t] = ls; ls += xv[t]; }
    float inc = ls;
    #pragma unroll
    for (int off = 1; off < 64; off <<= 1) {
        const float tmp = __shfl_up(inc, off, 64);
        if (lane >= off) inc += tmp;
    }
    const float exoff = inc - ls;
    #pragma unroll
    for (int t = 0; t < 8; ++t) a[base + t] = exoff + e[t];
}

__device__ inline void scan512_suf(float* a) {   // inclusive suffix, small-first
    const int lane = threadIdx.x & 63;
    const int base = lane * 8;
    float xv[8], e[8]; float ls = 0.f;
    #pragma unroll
    for (int t = 0; t < 8; ++t) xv[t] = a[base + t];
    #pragma unroll
    for (int t = 7; t >= 0; --t) { e[t] = ls; ls += xv[t]; }
    float inc = ls;
    #pragma unroll
    for (int off = 1; off < 64; off <<= 1) {
        const float tmp = __shfl_down(inc, off, 64);
        if (lane + off < 64) inc += tmp;
    }
    const float exoff = inc - ls;
    #pragma unroll
    for (int t = 0; t < 8; ++t) a[base + t] = exoff + e[t] + xv[t];
}

__device__ inline void scan512_i(const int* cntA, int* begA, int* curA) {
    const int lane = threadIdx.x & 63;
    const int base = lane * 8;
    int xv[8], e[8]; int ls = 0;
    #pragma unroll
    for (int t = 0; t < 8; ++t) xv[t] = cntA[base + t];
    #pragma unroll
    for (int t = 0; t < 8; ++t) { e[t] = ls; ls += xv[t]; }
    int inc = ls;
    #pragma unroll
    for (int off = 1; off < 64; off <<= 1) {
        const int tmp = __shfl_up(inc, off, 64);
        if (lane >= off) inc += tmp;
    }
    const int exoff = inc - ls;
    #pragma unroll
    for (int t = 0; t < 8; ++t) {
        begA[base + t] = exoff + e[t];
        curA[base + t] = exoff + e[t];
    }
}

__global__ __launch_bounds__(BLOCK) void deformer_one(
    const float* __restrict__ x,
    const float* __restrict__ dverts,
    const float* __restrict__ mverts,
    float* __restrict__ out)
{
    // bucket-grouped per-vert tuples
    __shared__ float sV[M], sAp[M], sSp[M], sAm[M], sSm[M];      // 20 KB
    // per-bucket aggregates; after scans: Ap/Sp = exclusive prefix,
    // Am/Sm = inclusive suffix (both accumulated tiny-terms-first).
    __shared__ float gAp[K], gSp[K], gAm[K], gSm[K];             // 8 KB
    __shared__ int   cnt[K], beg[K], cur[K];                      // 6 KB

    const int tid = threadIdx.x;
    const int p = blockIdx.x >> 5;    // pair 0..5
    const int c = blockIdx.x & 31;    // chunk within pair
    const int b = p / 3, d = p % 3;

    for (int i = tid; i < K; i += BLOCK) {
        cnt[i] = 0; gAp[i] = 0.f; gSp[i] = 0.f; gAm[i] = 0.f; gSm[i] = 0.f;
    }
    __syncthreads();

    // ---- Build: 4 verts/thread; tuples stay in registers until scatter ----
    float vv[4], ap[4], sp[4], am[4], sm[4]; int bj[4];
    #pragma unroll
    for (int u = 0; u < 4; ++u) {
        const int i = tid + u * BLOCK;
        const int g = (b * M_FULL + i * SUBDIV) * D + d;
        const float v = dverts[g];
        const float w = mverts[g];
        const float epv = __builtin_amdgcn_exp2f( K4 * v);   // e^{4v}
        const float emv = __builtin_amdgcn_exp2f(-K4 * v);   // e^{-4v}
        vv[u] = v;
        ap[u] = w * epv; sp[u] = epv;
        am[u] = w * emv; sm[u] = emv;
        int j = (int)floorf((v - LO) * INV_W);
        j = j < 0 ? 0 : (j > K - 1 ? K - 1 : j);
        bj[u] = j;
        atomicAdd(&cnt[j], 1);
        atomicAdd(&gAp[j], ap[u]);
        atomicAdd(&gSp[j], sp[u]);
        atomicAdd(&gAm[j], am[u]);
        atomicAdd(&gSm[j], sm[u]);
    }
    __syncthreads();

    // Scans: 4 waves cover 5 scans (wave 0 does two disjoint ones).
    const int wid = tid >> 6;
    if (wid == 0)      { scan512_i(cnt, beg, cur); scan512_suf(gSm); }
    else if (wid == 1) scan512_pre(gAp);
    else if (wid == 2) scan512_pre(gSp);
    else               scan512_suf(gAm);
    __syncthreads();

    // Counting scatter into bucket-grouped order.
    #pragma unroll
    for (int u = 0; u < 4; ++u) {
        const int pos = atomicAdd(&cur[bj[u]], 1);
        sV[pos] = vv[u]; sAp[pos] = ap[u]; sSp[pos] = sp[u];
        sAm[pos] = am[u]; sSm[pos] = sm[u];
    }
    __syncthreads();

    // ---- Query phase: QPT output elements per thread ----
    #pragma unroll
    for (int u = 0; u < QPT; ++u) {
        const int n = (c * QPT + u) * BLOCK + tid;
        const int o = (b * N + n) * D + d;
        const float xq = x[o];

        int j = (int)floorf((xq - LO) * INV_W);
        j = j < 0 ? 0 : (j > K - 1 ? K - 1 : j);

        const float en  = __builtin_amdgcn_exp2f(-K4 * xq);  // e^{-4x}
        const float epx = __builtin_amdgcn_exp2f( K4 * xq);  // e^{+4x}

        const float Ap = gAp[j];                          // buckets strictly below j
        const float Sp = gSp[j];
        const float Am = (j < K - 1) ? gAm[j + 1] : 0.f;  // buckets strictly above j
        const float Sm = (j < K - 1) ? gSm[j + 1] : 0.f;

        const int s0 = beg[j], s1 = s0 + cnt[j];
        float rAp = 0.f, rSp = 0.f, rAm = 0.f, rSm = 0.f;
        for (int i = s0; i < s1; ++i) {
            const bool le = (sV[i] <= xq);
            rAp += le ? sAp[i] : 0.f;
            rSp += le ? sSp[i] : 0.f;
            rAm += le ? 0.f : sAm[i];
            rSm += le ? 0.f : sSm[i];
        }
        out[o] = (en * (Ap + rAp) + epx * (Am + rAm)) /
                 (en * (Sp + rSp) + epx * (Sm + rSm));
    }
}

extern "C" void kernel_launch(void* const* d_in, const int* in_sizes, int n_in,
                              void* d_out, int out_size, void* d_ws, size_t ws_size,
                              hipStream_t stream) {
    const float* x  = (const float*)d_in[0];
    const float* dv = (const float*)d_in[1];
    const float* mv = (const float*)d_in[2];
    float* out = (float*)d_out;

    deformer_one<<<GRID, BLOCK, 0, stream>>>(x, dv, mv, out);
}

// Round 7
// 67.559 us; speedup vs baseline: 2.6133x; 1.0867x over previous
//
#include <hip/hip_runtime.h>
#include <math.h>

// Problem constants (fixed by setup_inputs)
constexpr int B       = 2;
constexpr int N       = 32768;
constexpr int D       = 3;
constexpr int M_FULL  = 8192;
constexpr int SUBDIV  = 8;
constexpr int M       = M_FULL / SUBDIV;   // 1024 subsampled verts per (b,d)
constexpr int K       = 512;               // value buckets over [-4,4]
constexpr float LO    = -4.0f;
constexpr float INV_W = 64.0f;             // 1 / (8/512)
constexpr int BLOCK   = 1024;              // 16 waves/CU: latency hiding for build+query
constexpr int CHUNKS  = N / BLOCK;         // 32 blocks per (b,d) pair
constexpr int GRID    = B * D * CHUNKS;    // 192 blocks -> 1 per CU
constexpr float K4    = 5.770780163555852f; // 4*log2(e): e^{4t} = 2^{K4*t}

// ---- 512-element wave-parallel scans (one wave, lane owns 8 slots) ----
__device__ inline void scan512_pre(float* a) {   // exclusive prefix, small-first
    const int lane = threadIdx.x & 63;
    const int base = lane * 8;
    float xv[8], e[8]; float ls = 0.f;
    #pragma unroll
    for (int t = 0; t < 8; ++t) xv[t] = a[base + t];
    #pragma unroll
    for (int t = 0; t < 8; ++t) { e[t] = ls; ls += xv[t]; }
    float inc = ls;
    #pragma unroll
    for (int off = 1; off < 64; off <<= 1) {
        const float tmp = __shfl_up(inc, off, 64);
        if (lane >= off) inc += tmp;
    }
    const float exoff = inc - ls;
    #pragma unroll
    for (int t = 0; t < 8; ++t) a[base + t] = exoff + e[t];
}

__device__ inline void scan512_suf(float* a) {   // inclusive suffix, small-first
    const int lane = threadIdx.x & 63;
    const int base = lane * 8;
    float xv[8], e[8]; float ls = 0.f;
    #pragma unroll
    for (int t = 0; t < 8; ++t) xv[t] = a[base + t];
    #pragma unroll
    for (int t = 7; t >= 0; --t) { e[t] = ls; ls += xv[t]; }
    float inc = ls;
    #pragma unroll
    for (int off = 1; off < 64; off <<= 1) {
        const float tmp = __shfl_down(inc, off, 64);
        if (lane + off < 64) inc += tmp;
    }
    const float exoff = inc - ls;
    #pragma unroll
    for (int t = 0; t < 8; ++t) a[base + t] = exoff + e[t] + xv[t];
}

__device__ inline void scan512_i(const int* cntA, int* begA, int* curA) {
    const int lane = threadIdx.x & 63;
    const int base = lane * 8;
    int xv[8], e[8]; int ls = 0;
    #pragma unroll
    for (int t = 0; t < 8; ++t) xv[t] = cntA[base + t];
    #pragma unroll
    for (int t = 0; t < 8; ++t) { e[t] = ls; ls += xv[t]; }
    int inc = ls;
    #pragma unroll
    for (int off = 1; off < 64; off <<= 1) {
        const int tmp = __shfl_up(inc, off, 64);
        if (lane >= off) inc += tmp;
    }
    const int exoff = inc - ls;
    #pragma unroll
    for (int t = 0; t < 8; ++t) {
        begA[base + t] = exoff + e[t];
        curA[base + t] = exoff + e[t];
    }
}

__global__ __launch_bounds__(BLOCK) void deformer_one(
    const float* __restrict__ x,
    const float* __restrict__ dverts,
    const float* __restrict__ mverts,
    float* __restrict__ out)
{
    // bucket-grouped per-vert tuples
    __shared__ float sV[M], sAp[M], sSp[M], sAm[M], sSm[M];      // 20 KB
    // per-bucket aggregates; after scans: Ap/Sp = exclusive prefix,
    // Am/Sm = inclusive suffix (both accumulated tiny-terms-first).
    __shared__ float gAp[K], gSp[K], gAm[K], gSm[K];             // 8 KB
    __shared__ int   cnt[K], beg[K], cur[K];                      // 6 KB

    const int tid = threadIdx.x;
    const int p = blockIdx.x >> 5;    // pair 0..5
    const int c = blockIdx.x & 31;    // chunk within pair
    const int b = p / 3, d = p % 3;

    if (tid < K) {
        cnt[tid] = 0; gAp[tid] = 0.f; gSp[tid] = 0.f; gAm[tid] = 0.f; gSm[tid] = 0.f;
    }
    __syncthreads();

    // ---- Build: one vert per thread (M == BLOCK) ----
    const int g = (b * M_FULL + tid * SUBDIV) * D + d;
    const float v = dverts[g];
    const float w = mverts[g];
    const float epv = __builtin_amdgcn_exp2f( K4 * v);   // e^{4v}
    const float emv = __builtin_amdgcn_exp2f(-K4 * v);   // e^{-4v}
    const float ap = w * epv, sp = epv;
    const float am = w * emv, sm = emv;
    int bj = (int)floorf((v - LO) * INV_W);
    bj = bj < 0 ? 0 : (bj > K - 1 ? K - 1 : bj);
    atomicAdd(&cnt[bj], 1);
    atomicAdd(&gAp[bj], ap);
    atomicAdd(&gSp[bj], sp);
    atomicAdd(&gAm[bj], am);
    atomicAdd(&gSm[bj], sm);
    __syncthreads();

    // Scans: 5 scans on 5 separate waves, concurrent.
    const int wid = tid >> 6;
    if      (wid == 0) scan512_i(cnt, beg, cur);
    else if (wid == 1) scan512_pre(gAp);
    else if (wid == 2) scan512_pre(gSp);
    else if (wid == 3) scan512_suf(gAm);
    else if (wid == 4) scan512_suf(gSm);
    __syncthreads();

    // Counting scatter into bucket-grouped order.
    const int pos = atomicAdd(&cur[bj], 1);
    sV[pos] = v; sAp[pos] = ap; sSp[pos] = sp;
    sAm[pos] = am; sSm[pos] = sm;
    __syncthreads();

    // ---- Query: one output element per thread ----
    const int n = c * BLOCK + tid;
    const int o = (b * N + n) * D + d;
    const float xq = x[o];

    int j = (int)floorf((xq - LO) * INV_W);
    j = j < 0 ? 0 : (j > K - 1 ? K - 1 : j);

    const float en  = __builtin_amdgcn_exp2f(-K4 * xq);  // e^{-4x}
    const float epx = __builtin_amdgcn_exp2f( K4 * xq);  // e^{+4x}

    const float Ap = gAp[j];                          // buckets strictly below j
    const float Sp = gSp[j];
    const float Am = (j < K - 1) ? gAm[j + 1] : 0.f;  // buckets strictly above j
    const float Sm = (j < K - 1) ? gSm[j + 1] : 0.f;

    const int s0 = beg[j], s1 = s0 + cnt[j];
    float rAp = 0.f, rSp = 0.f, rAm = 0.f, rSm = 0.f;
    for (int i = s0; i < s1; ++i) {
        const bool le = (sV[i] <= xq);
        rAp += le ? sAp[i] : 0.f;
        rSp += le ? sSp[i] : 0.f;
        rAm += le ? 0.f : sAm[i];
        rSm += le ? 0.f : sSm[i];
    }
    out[o] = (en * (Ap + rAp) + epx * (Am + rAm)) /
             (en * (Sp + rSp) + epx * (Sm + rSm));
}

extern "C" void kernel_launch(void* const* d_in, const int* in_sizes, int n_in,
                              void* d_out, int out_size, void* d_ws, size_t ws_size,
                              hipStream_t stream) {
    const float* x  = (const float*)d_in[0];
    const float* dv = (const float*)d_in[1];
    const float* mv = (const float*)d_in[2];
    float* out = (float*)d_out;

    deformer_one<<<GRID, BLOCK, 0, stream>>>(x, dv, mv, out);
}